// Round 3
// baseline (104.745 us; speedup 1.0000x reference)
//
#include <hip/hip_runtime.h>

// RelationAttention: B=8, S=512, H=256, A=64
//   scores[b,i,j] = sum_a v[a]*tanh(ta[b,i,a]+ja[b,j,a]+b[a]); out = softmax_j
//
// tanh(x) = 1 - 2/(1+e^{2x});  e^{2(ta+b+ja)} = Et * Ej with
//   Et = exp(2*(ta+b))  stored (B,S,A)
//   Ej = exp(2*ja)      stored interleaved (B, A/4, S, 4) so stage-2's inner
//                       load is one coalesced float4 (4 a-values for lane's j)
// score = sum(v) - 2 * sum_a v[a] * rcp(1 + Et*Ej)
// Overflow-safe: Et*Ej -> inf => rcp->0 => tanh->1; ->0 => rcp(1)=1 => tanh->-1.

#define B_ 8
#define S_ 512
#define H_ 256
#define A_ 64

// ---------------- Stage 1: projections + exp precompute ----------------
// grid = 512 (64 row-blocks x 8 col-blocks of 16), block = 256 (4 waves).
// LDS tile is TRANSPOSED rt[k][row] with +1 pad:
//   compute read rt[k][lane]: bank=(k+lane)%32 -> 2-way = free
//   staging write rt[4q+i][r]: bank=(4q+i+r)%32 -> 2-way = free
// w columns are wave-uniform (readfirstlane) -> s_load streams, zero gathers.
__global__ __launch_bounds__(256) void rel_stage1(
    const float* __restrict__ rh, const float* __restrict__ wta,
    const float* __restrict__ wja, const float* __restrict__ bias,
    float* __restrict__ ta2e, float* __restrict__ ej) {
  __shared__ float rt[64][65];  // 16.6 KB
  const int t = threadIdx.x;
  const int cb = blockIdx.x & 7;   // col-block (16 cols)
  const int rb = blockIdx.x >> 3;  // row-block (64 rows)
  const int row0 = rb << 6;
  const int lane = t & 63;
  // combined col 0..127 (0..63 -> w_ta, 64..127 -> w_ja), wave-uniform
  const int cg = __builtin_amdgcn_readfirstlane(cb * 16 + ((t >> 6) << 2));
  const float* wbase = (cg < A_) ? (wta + (size_t)cg * H_)
                                 : (wja + (size_t)(cg - A_) * H_);
  const float* w0 = wbase;
  const float* w1 = wbase + H_;
  const float* w2 = wbase + 2 * H_;
  const float* w3 = wbase + 3 * H_;

  const int sr = t >> 4;        // staging row 0..15 (+16 per i)
  const int sq = t & 15;        // staging quad within row

  float4 acc = {0.f, 0.f, 0.f, 0.f};
  for (int kt = 0; kt < H_; kt += 64) {
    if (kt) __syncthreads();  // protect previous tile's readers
#pragma unroll
    for (int i = 0; i < 4; ++i) {
      const int r = sr + (i << 4);
      const float4 x =
          *(const float4*)&rh[(size_t)(row0 + r) * H_ + kt + (sq << 2)];
      rt[(sq << 2) + 0][r] = x.x;
      rt[(sq << 2) + 1][r] = x.y;
      rt[(sq << 2) + 2][r] = x.z;
      rt[(sq << 2) + 3][r] = x.w;
    }
    __syncthreads();
#pragma unroll 16
    for (int k = 0; k < 64; ++k) {
      const float x = rt[k][lane];
      const int kk = kt + k;
      acc.x = __builtin_fmaf(x, w0[kk], acc.x);
      acc.y = __builtin_fmaf(x, w1[kk], acc.y);
      acc.z = __builtin_fmaf(x, w2[kk], acc.z);
      acc.w = __builtin_fmaf(x, w3[kk], acc.w);
    }
  }

  const int row = row0 + lane;
  if (cg < A_) {  // 'ta' columns: Et = exp(2*(ta + bias)), layout (B,S,A)
    float4 e;
    e.x = __expf(2.f * (acc.x + bias[cg + 0]));
    e.y = __expf(2.f * (acc.y + bias[cg + 1]));
    e.z = __expf(2.f * (acc.z + bias[cg + 2]));
    e.w = __expf(2.f * (acc.w + bias[cg + 3]));
    *(float4*)&ta2e[(size_t)row * A_ + cg] = e;
  } else {  // 'ja' columns: Ej = exp(2*ja), layout (B, A/4, S, 4)
    const int a0 = cg - A_;
    const int bidx = row >> 9;
    const int s = row & (S_ - 1);
    float4 e;
    e.x = __expf(2.f * acc.x);
    e.y = __expf(2.f * acc.y);
    e.z = __expf(2.f * acc.z);
    e.w = __expf(2.f * acc.w);
    *(float4*)&ej[((((size_t)bidx * 16 + (a0 >> 2)) * S_ + s) << 2)] = e;
  }
}

// ---------------- Stage 2: rcp-reduce + softmax ----------------
// grid = 1024 blocks (4 query rows each), block = 512 threads (thread = j).
// Et rows + v staged to LDS once (broadcast reads, conflict-free); only Ej
// is a per-lane vector load. unroll 4 bounds live VGPRs (no spill).
__global__ __launch_bounds__(512) void rel_stage2(
    const float* __restrict__ ta2e, const float* __restrict__ ej,
    const float* __restrict__ v, float* __restrict__ out) {
  __shared__ __align__(16) float tai[4][A_];
  __shared__ __align__(16) float vv[A_];
  __shared__ float red[4][8];
  const int t = threadIdx.x;
  const int row0 = blockIdx.x << 2;  // global row = b*S + i
  const int bidx = row0 >> 9;
  if (t < 4 * A_) tai[t >> 6][t & 63] = ta2e[(size_t)row0 * A_ + t];
  else if (t < 4 * A_ + A_) vv[t - 4 * A_] = v[t - 4 * A_];
  __syncthreads();

  float vsum = 0.f;
#pragma unroll
  for (int a = 0; a < A_; a += 4) {  // broadcast LDS reads
    const float4 x = *(const float4*)&vv[a];
    vsum += x.x + x.y + x.z + x.w;
  }

  float acc0 = 0.f, acc1 = 0.f, acc2 = 0.f, acc3 = 0.f;
  const float* ejb = ej + (((size_t)bidx * 16) * S_ << 2) + (t << 2);
#pragma unroll 4
  for (int g = 0; g < 16; ++g) {
    const float4 E = *(const float4*)(ejb + ((size_t)g * S_ << 2));
    const float4 V = *(const float4*)&vv[g << 2];
    const float4 T0 = *(const float4*)&tai[0][g << 2];
    const float4 T1 = *(const float4*)&tai[1][g << 2];
    const float4 T2 = *(const float4*)&tai[2][g << 2];
    const float4 T3 = *(const float4*)&tai[3][g << 2];
    acc0 += V.x * __builtin_amdgcn_rcpf(__builtin_fmaf(T0.x, E.x, 1.f))
          + V.y * __builtin_amdgcn_rcpf(__builtin_fmaf(T0.y, E.y, 1.f))
          + V.z * __builtin_amdgcn_rcpf(__builtin_fmaf(T0.z, E.z, 1.f))
          + V.w * __builtin_amdgcn_rcpf(__builtin_fmaf(T0.w, E.w, 1.f));
    acc1 += V.x * __builtin_amdgcn_rcpf(__builtin_fmaf(T1.x, E.x, 1.f))
          + V.y * __builtin_amdgcn_rcpf(__builtin_fmaf(T1.y, E.y, 1.f))
          + V.z * __builtin_amdgcn_rcpf(__builtin_fmaf(T1.z, E.z, 1.f))
          + V.w * __builtin_amdgcn_rcpf(__builtin_fmaf(T1.w, E.w, 1.f));
    acc2 += V.x * __builtin_amdgcn_rcpf(__builtin_fmaf(T2.x, E.x, 1.f))
          + V.y * __builtin_amdgcn_rcpf(__builtin_fmaf(T2.y, E.y, 1.f))
          + V.z * __builtin_amdgcn_rcpf(__builtin_fmaf(T2.z, E.z, 1.f))
          + V.w * __builtin_amdgcn_rcpf(__builtin_fmaf(T2.w, E.w, 1.f));
    acc3 += V.x * __builtin_amdgcn_rcpf(__builtin_fmaf(T3.x, E.x, 1.f))
          + V.y * __builtin_amdgcn_rcpf(__builtin_fmaf(T3.y, E.y, 1.f))
          + V.z * __builtin_amdgcn_rcpf(__builtin_fmaf(T3.z, E.z, 1.f))
          + V.w * __builtin_amdgcn_rcpf(__builtin_fmaf(T3.w, E.w, 1.f));
  }
  float sc[4] = {vsum - 2.f * acc0, vsum - 2.f * acc1, vsum - 2.f * acc2,
                 vsum - 2.f * acc3};

  // softmax over j (512 threads), per row r
  const int lane = t & 63;
  const int wv = t >> 6;
#pragma unroll
  for (int r = 0; r < 4; ++r) {
    float m = sc[r];
#pragma unroll
    for (int off = 32; off; off >>= 1) m = fmaxf(m, __shfl_xor(m, off));
    if (lane == 0) red[r][wv] = m;
  }
  __syncthreads();
  float mx[4];
#pragma unroll
  for (int r = 0; r < 4; ++r) {
    float m = red[r][0];
#pragma unroll
    for (int i = 1; i < 8; ++i) m = fmaxf(m, red[r][i]);
    mx[r] = m;
  }
  __syncthreads();
  float ex[4];
#pragma unroll
  for (int r = 0; r < 4; ++r) {
    ex[r] = __expf(sc[r] - mx[r]);
    float s = ex[r];
#pragma unroll
    for (int off = 32; off; off >>= 1) s += __shfl_xor(s, off);
    if (lane == 0) red[r][wv] = s;
  }
  __syncthreads();
#pragma unroll
  for (int r = 0; r < 4; ++r) {
    float s = 0.f;
#pragma unroll
    for (int i = 0; i < 8; ++i) s += red[r][i];
    out[(size_t)(row0 + r) * S_ + t] = ex[r] * __builtin_amdgcn_rcpf(s);
  }
}

extern "C" void kernel_launch(void* const* d_in, const int* in_sizes, int n_in,
                              void* d_out, int out_size, void* d_ws, size_t ws_size,
                              hipStream_t stream) {
  const float* rh   = (const float*)d_in[0];  // (B,S,H)
  const float* wta  = (const float*)d_in[1];  // (A,H)
  const float* wja  = (const float*)d_in[2];  // (A,H)
  const float* bias = (const float*)d_in[3];  // (1,1,1,A)
  const float* v    = (const float*)d_in[4];  // (1,A)
  float* out = (float*)d_out;                 // (B,S,S)

  float* ta2e = (float*)d_ws;                 // B*S*A floats = 1 MB
  float* ej   = ta2e + (size_t)B_ * S_ * A_;  // B*A*S floats = 1 MB

  rel_stage1<<<dim3(512), dim3(256), 0, stream>>>(rh, wta, wja, bias, ta2e, ej);
  rel_stage2<<<dim3((B_ * S_) / 4), dim3(512), 0, stream>>>(ta2e, ej, v, out);
}

// Round 4
// 101.569 us; speedup vs baseline: 1.0313x; 1.0313x over previous
//
#include <hip/hip_runtime.h>

// RelationAttention: B=8, S=512, H=256, A=64
//   scores[b,i,j] = sum_a v[a]*tanh(ta[b,i,a]+ja[b,j,a]+b[a]); out = softmax_j
//
// tanh(x) = 1 - 2/(1+e^{2x});  e^{2(ta+b+ja)} = Et * Ej with
//   Et = exp(2*(ta+b))  stored (B,S,A)
//   Ej = exp(2*ja)      stored interleaved (B, A/4, S, 4) so stage-2's inner
//                       load is one coalesced float4 (4 a-values for lane's j)
// score = sum(v) + sum_a (-2*v[a]) * rcp(1 + Et*Ej)
// Overflow-safe: Et*Ej -> inf => rcp->0 => tanh->1; ->0 => rcp(1)=1 => tanh->-1.

#define B_ 8
#define S_ 512
#define H_ 256
#define A_ 64

// ---------------- Stage 1: projections + exp precompute ----------------
// grid = 512: rb = idx&63 (64-row block), cb = idx>>6 (16 combined cols).
// idx%8 == rb%8  => all 8 cb-blocks of one rb land on the SAME XCD -> rh is
// HBM-fetched once (8 MB), re-reads hit that XCD's L2.
// BOTH rh and w tiles staged in LDS; inner loop has ZERO scalar/global loads
// (no s_load/ds_read lgkmcnt serialization):
//   rt[k][row] (+1 pad): compute read rt[k][lane] stride-1, 2-way = free
//   ws[col][k]: wave-uniform col -> same-address broadcast b128 = free
__global__ __launch_bounds__(256) void rel_stage1(
    const float* __restrict__ rh, const float* __restrict__ wta,
    const float* __restrict__ wja, const float* __restrict__ bias,
    float* __restrict__ ta2e, float* __restrict__ ej) {
  __shared__ float rt[64][65];                 // 16.6 KB
  __shared__ __align__(16) float ws[16][68];   // 4.25 KB (stride 272B = 17*16)
  const int t = threadIdx.x;
  const int rb = blockIdx.x & 63;
  const int cb = blockIdx.x >> 6;
  const int row0 = rb << 6;
  const int lane = t & 63;
  const int cg0 = cb << 4;  // block's combined-col base (0..112), block-uniform
  const int cl = __builtin_amdgcn_readfirstlane((t >> 6) << 2);  // wave col base
  const float* wsrc = (cg0 < A_) ? (wta + (size_t)cg0 * H_)
                                 : (wja + (size_t)(cg0 - A_) * H_);
  const int sr = t >> 4, sq = t & 15;

  float4 acc = {0.f, 0.f, 0.f, 0.f};
  for (int kt = 0; kt < H_; kt += 64) {
    if (kt) __syncthreads();  // protect previous tile's readers
#pragma unroll
    for (int i = 0; i < 4; ++i) {  // rh tile: 4 float4 per thread, coalesced
      const int r = sr + (i << 4);
      const float4 x =
          *(const float4*)&rh[(size_t)(row0 + r) * H_ + kt + (sq << 2)];
      rt[(sq << 2) + 0][r] = x.x;
      rt[(sq << 2) + 1][r] = x.y;
      rt[(sq << 2) + 2][r] = x.z;
      rt[(sq << 2) + 3][r] = x.w;
    }
    {  // w tile: 16 cols x 64 k, 1 float4 per thread
      const float4 wx =
          *(const float4*)&wsrc[(size_t)sr * H_ + kt + (sq << 2)];
      *(float4*)&ws[sr][sq << 2] = wx;
    }
    __syncthreads();
#pragma unroll 4
    for (int k4 = 0; k4 < 16; ++k4) {
      const int k = k4 << 2;
      const float4 w0 = *(const float4*)&ws[cl + 0][k];  // broadcast b128
      const float4 w1 = *(const float4*)&ws[cl + 1][k];
      const float4 w2 = *(const float4*)&ws[cl + 2][k];
      const float4 w3 = *(const float4*)&ws[cl + 3][k];
      const float x0 = rt[k + 0][lane], x1 = rt[k + 1][lane];
      const float x2 = rt[k + 2][lane], x3 = rt[k + 3][lane];
      acc.x += x0 * w0.x + x1 * w0.y + x2 * w0.z + x3 * w0.w;
      acc.y += x0 * w1.x + x1 * w1.y + x2 * w1.z + x3 * w1.w;
      acc.z += x0 * w2.x + x1 * w2.y + x2 * w2.z + x3 * w2.w;
      acc.w += x0 * w3.x + x1 * w3.y + x2 * w3.z + x3 * w3.w;
    }
  }

  const int row = row0 + lane;
  const int cg = cg0 + cl;  // combined col 0..127, wave-uniform
  if (cg < A_) {  // 'ta' columns: Et = exp(2*(ta + bias)), layout (B,S,A)
    float4 e;
    e.x = __expf(2.f * (acc.x + bias[cg + 0]));
    e.y = __expf(2.f * (acc.y + bias[cg + 1]));
    e.z = __expf(2.f * (acc.z + bias[cg + 2]));
    e.w = __expf(2.f * (acc.w + bias[cg + 3]));
    *(float4*)&ta2e[(size_t)row * A_ + cg] = e;
  } else {  // 'ja' columns: Ej = exp(2*ja), layout (B, A/4, S, 4)
    const int a0 = cg - A_;
    const int bidx = row >> 9;
    const int s = row & (S_ - 1);
    float4 e;
    e.x = __expf(2.f * acc.x);
    e.y = __expf(2.f * acc.y);
    e.z = __expf(2.f * acc.z);
    e.w = __expf(2.f * acc.w);
    *(float4*)&ej[((((size_t)bidx * 16 + (a0 >> 2)) * S_ + s) << 2)] = e;
  }
}

// ---------------- Stage 2: rcp-reduce + softmax ----------------
// grid = 512 blocks (8 query rows each -> halves Ej traffic vs 4 rows),
// block = 512 threads (thread = j). Et rows + (-2v) staged in LDS once;
// all inner LDS reads are same-address broadcasts (free). Only Ej is a
// per-lane vector load (fully coalesced float4). VGPR ~50, no spill.
__global__ __launch_bounds__(512) void rel_stage2(
    const float* __restrict__ ta2e, const float* __restrict__ ej,
    const float* __restrict__ v, float* __restrict__ out) {
  __shared__ __align__(16) float tai[8][A_];  // 2 KB
  __shared__ __align__(16) float vm[A_];      // -2*v
  __shared__ float red[8][8];
  const int t = threadIdx.x;
  const int row0 = blockIdx.x << 3;  // global row = b*S + i
  const int bidx = row0 >> 9;
  tai[t >> 6][t & 63] = ta2e[(size_t)row0 * A_ + t];  // exactly 512 floats
  if (t < A_) vm[t] = -2.f * v[t];
  __syncthreads();

  float vsum = 0.f;
#pragma unroll
  for (int a = 0; a < A_; a += 4) {  // broadcast LDS reads
    const float4 x = *(const float4*)&vm[a];
    vsum += x.x + x.y + x.z + x.w;
  }
  vsum *= -0.5f;  // sum(v)

  float acc[8] = {0.f, 0.f, 0.f, 0.f, 0.f, 0.f, 0.f, 0.f};
  const float* ejb = ej + (((size_t)bidx * 16) * S_ << 2) + (t << 2);
#pragma unroll 2
  for (int g = 0; g < 16; ++g) {
    const float4 E = *(const float4*)(ejb + ((size_t)g * S_ << 2));
    const float4 V = *(const float4*)&vm[g << 2];
#pragma unroll
    for (int r = 0; r < 8; ++r) {
      const float4 T = *(const float4*)&tai[r][g << 2];
      acc[r] += V.x * __builtin_amdgcn_rcpf(__builtin_fmaf(T.x, E.x, 1.f))
              + V.y * __builtin_amdgcn_rcpf(__builtin_fmaf(T.y, E.y, 1.f))
              + V.z * __builtin_amdgcn_rcpf(__builtin_fmaf(T.z, E.z, 1.f))
              + V.w * __builtin_amdgcn_rcpf(__builtin_fmaf(T.w, E.w, 1.f));
    }
  }
  float sc[8];
#pragma unroll
  for (int r = 0; r < 8; ++r) sc[r] = vsum + acc[r];

  // softmax over j (512 threads), per row r
  const int lane = t & 63;
  const int wv = t >> 6;
#pragma unroll
  for (int r = 0; r < 8; ++r) {
    float m = sc[r];
#pragma unroll
    for (int off = 32; off; off >>= 1) m = fmaxf(m, __shfl_xor(m, off));
    if (lane == 0) red[r][wv] = m;
  }
  __syncthreads();
  float mx[8];
#pragma unroll
  for (int r = 0; r < 8; ++r) {
    float m = red[r][0];
#pragma unroll
    for (int i = 1; i < 8; ++i) m = fmaxf(m, red[r][i]);
    mx[r] = m;
  }
  __syncthreads();
  float ex[8];
#pragma unroll
  for (int r = 0; r < 8; ++r) {
    ex[r] = __expf(sc[r] - mx[r]);
    float s = ex[r];
#pragma unroll
    for (int off = 32; off; off >>= 1) s += __shfl_xor(s, off);
    if (lane == 0) red[r][wv] = s;
  }
  __syncthreads();
#pragma unroll
  for (int r = 0; r < 8; ++r) {
    float s = 0.f;
#pragma unroll
    for (int i = 0; i < 8; ++i) s += red[r][i];
    out[(size_t)(row0 + r) * S_ + t] = ex[r] * __builtin_amdgcn_rcpf(s);
  }
}

extern "C" void kernel_launch(void* const* d_in, const int* in_sizes, int n_in,
                              void* d_out, int out_size, void* d_ws, size_t ws_size,
                              hipStream_t stream) {
  const float* rh   = (const float*)d_in[0];  // (B,S,H)
  const float* wta  = (const float*)d_in[1];  // (A,H)
  const float* wja  = (const float*)d_in[2];  // (A,H)
  const float* bias = (const float*)d_in[3];  // (1,1,1,A)
  const float* v    = (const float*)d_in[4];  // (1,A)
  float* out = (float*)d_out;                 // (B,S,S)

  float* ta2e = (float*)d_ws;                 // B*S*A floats = 1 MB
  float* ej   = ta2e + (size_t)B_ * S_ * A_;  // B*A*S floats = 1 MB

  rel_stage1<<<dim3(512), dim3(256), 0, stream>>>(rh, wta, wja, bias, ta2e, ej);
  rel_stage2<<<dim3((B_ * S_) / 8), dim3(512), 0, stream>>>(ta2e, ej, v, out);
}